// Round 13
// baseline (53.005 us; speedup 1.0000x reference)
//
#include <hip/hip_runtime.h>
#include <stdint.h>

#define BATCH   32768
#define NBITS   512
#define NWORDS  512          // BATCH / 64
#define NSLICE  32           // K-split: 36 tiles * 32 = 1152 blocks
#define SW      16           // words per slice = NWORDS / NSLICE
#define NTILE   36           // 8x8 lower-triangle of 64x64 tiles
#define MIGRID  512

typedef unsigned long long u64;

// ---------------------------------------------------------------------------
// Pass 1: bit-pack, float4-read version (measured ~11 us @ BW roofline, R11)
// now storing straight into the u64 word layout gram wants: the four u32
// masks of (word w, cols c0..c0+3, row-half h) are the lo (h=0) / hi (h=1)
// dwords of packed[w*512+c] -> 4 interleaved dword stores. Write traffic is
// 2 MB vs 64 MB read, so scatter stores are noise. Also lg table + zeroing.
// ---------------------------------------------------------------------------
__global__ __launch_bounds__(256) void pack_kernel(const float* __restrict__ bits,
                                                   u64* __restrict__ packed,
                                                   double* __restrict__ lg,
                                                   int* __restrict__ c1,
                                                   int* __restrict__ done) {
    const int gid = blockIdx.x * 256 + threadIdx.x;   // 0..131071

    if (gid <= BATCH) lg[gid] = (gid > 0) ? log((double)gid) : 0.0;
    if (gid < NBITS) c1[gid] = 0;
    if (gid == NBITS) *done = 0;

    const int wid  = threadIdx.x >> 6;
    const int lane = threadIdx.x & 63;
    const int gw   = blockIdx.x * 4 + wid;    // 0..2047
    const int w    = gw >> 2;                 // word 0..511
    const int h    = (gw >> 1) & 1;           // row half (0: rows 0-31, 1: 32-63)
    const int q    = gw & 1;                  // column half
    const int c0   = q * 256 + lane * 4;

    const float* base = bits + ((size_t)w * 64 + h * 32) * NBITS + c0;

    unsigned int m0 = 0, m1 = 0, m2 = 0, m3 = 0;
#pragma unroll 16
    for (int r = 0; r < 32; ++r) {
        float4 v = *reinterpret_cast<const float4*>(base + (size_t)r * NBITS);
        const unsigned int b = 1u << r;
        if (v.x > 0.0f) m0 |= b;
        if (v.y > 0.0f) m1 |= b;
        if (v.z > 0.0f) m2 |= b;
        if (v.w > 0.0f) m3 |= b;
    }
    // packed[w*512+c] lo dword = rows 0-31 (h=0), hi dword = rows 32-63 (h=1)
    unsigned int* p32 = reinterpret_cast<unsigned int*>(packed);
    const size_t b32 = ((size_t)w * NBITS + c0) * 2 + h;
    p32[b32 + 0] = m0;
    p32[b32 + 2] = m1;
    p32[b32 + 4] = m2;
    p32[b32 + 6] = m3;
}

// ---------------------------------------------------------------------------
// Pass 2: partial Gram — byte-identical to the MEASURED kernel (R10: 12.6 us,
// 75% VALUBusy, 0 bank conflicts). Block = (tile t of 36 [64x64], slice s of
// 32 [16 words]), 256 threads, 4x4 register tile, interleaved cols
// {x,x+1,x+32,x+33}, ulonglong2 staging from the u64 packed layout.
// ---------------------------------------------------------------------------
__global__ __launch_bounds__(256) void gram_kernel(const u64* __restrict__ packed,
                                                   unsigned short* __restrict__ Cp,
                                                   int* __restrict__ c1) {
    __shared__ u64 ldsI[SW][64];
    __shared__ u64 ldsJ[SW][64];

    const int s = blockIdx.x & (NSLICE - 1);  // K-slice 0..31
    const int t = blockIdx.x >> 5;            // tile 0..35
    int bi = (int)((sqrtf(8.0f * (float)t + 1.0f) - 1.0f) * 0.5f);
    while ((bi + 1) * (bi + 2) / 2 <= t) ++bi;
    while (bi * (bi + 1) / 2 > t) --bi;
    const int bj = t - bi * (bi + 1) / 2;

    const int i0 = bi * 64, j0 = bj * 64;
    const int w0 = s * SW;
    const bool diag = (bi == bj);

    for (int q = threadIdx.x; q < SW * 32; q += 256) {
        const int wo = q >> 5, cp = (q & 31) * 2;
        const size_t g = (size_t)(w0 + wo) * NBITS;
        *reinterpret_cast<ulonglong2*>(&ldsI[wo][cp]) =
            *reinterpret_cast<const ulonglong2*>(&packed[g + i0 + cp]);
        if (!diag)
            *reinterpret_cast<ulonglong2*>(&ldsJ[wo][cp]) =
                *reinterpret_cast<const ulonglong2*>(&packed[g + j0 + cp]);
    }
    __syncthreads();

    const int tj2 = (threadIdx.x & 15) * 2;
    const int ti2 = (threadIdx.x >> 4) * 2;
    const u64 (*BJ)[64] = diag ? ldsI : ldsJ;

    int acc[4][4] = {};
#pragma unroll
    for (int w = 0; w < SW; ++w) {
        const u64 a0 = ldsI[w][ti2],      a1 = ldsI[w][ti2 + 1];
        const u64 a2 = ldsI[w][ti2 + 32], a3 = ldsI[w][ti2 + 33];
        const u64 b0 = BJ[w][tj2],        b1 = BJ[w][tj2 + 1];
        const u64 b2 = BJ[w][tj2 + 32],   b3 = BJ[w][tj2 + 33];
        acc[0][0] += __popcll(a0 & b0); acc[0][1] += __popcll(a0 & b1);
        acc[0][2] += __popcll(a0 & b2); acc[0][3] += __popcll(a0 & b3);
        acc[1][0] += __popcll(a1 & b0); acc[1][1] += __popcll(a1 & b1);
        acc[1][2] += __popcll(a1 & b2); acc[1][3] += __popcll(a1 & b3);
        acc[2][0] += __popcll(a2 & b0); acc[2][1] += __popcll(a2 & b1);
        acc[2][2] += __popcll(a2 & b2); acc[2][3] += __popcll(a2 & b3);
        acc[3][0] += __popcll(a3 & b0); acc[3][1] += __popcll(a3 & b1);
        acc[3][2] += __popcll(a3 & b2); acc[3][3] += __popcll(a3 & b3);
    }

    unsigned short* out = Cp + ((size_t)s << 18);
    const int io[4] = {ti2, ti2 + 1, ti2 + 32, ti2 + 33};
#pragma unroll
    for (int a = 0; a < 4; ++a) {
        const size_t row = (size_t)(i0 + io[a]) * NBITS + j0;
        ushort2 u;
        u.x = (unsigned short)acc[a][0]; u.y = (unsigned short)acc[a][1];
        *reinterpret_cast<ushort2*>(&out[row + tj2]) = u;
        u.x = (unsigned short)acc[a][2]; u.y = (unsigned short)acc[a][3];
        *reinterpret_cast<ushort2*>(&out[row + tj2 + 32]) = u;
    }

    if (diag && ti2 == tj2) {
#pragma unroll
        for (int a = 0; a < 4; ++a)
            atomicAdd(&c1[i0 + io[a]], acc[a][a]);
    }
}

// ---------------------------------------------------------------------------
// Pass 3 (+fused final): per-pair MI terms (measured ~2.4 us + tail).
// ---------------------------------------------------------------------------
__global__ __launch_bounds__(256) void mi_kernel(const unsigned short* __restrict__ Cp,
                                                 const int* __restrict__ c1,
                                                 const double* __restrict__ lg,
                                                 double* __restrict__ bsum,
                                                 int* __restrict__ bcnt,
                                                 int* __restrict__ done,
                                                 float* __restrict__ out) {
    const double invB = 1.0 / (double)BATCH;
    const int i = blockIdx.x;
    const int ci = c1[i];
    const double lgB = lg[BATCH];
    double lsum = 0.0;
    int lcnt = 0;

#pragma unroll
    for (int half = 0; half < 2; ++half) {
        const int j = half * 256 + threadIdx.x;
        if (j < i) {
            int n11 = 0;
#pragma unroll
            for (int s = 0; s < NSLICE; ++s)
                n11 += Cp[((size_t)s << 18) + (size_t)i * NBITS + j];
            const int cj = c1[j];

            const int pim[2] = {BATCH - ci, ci};
            const int pjn[2] = {BATCH - cj, cj};
            const int nmn[2][2] = {{BATCH - ci - cj + n11, cj - n11},
                                   {ci - n11, n11}};
#pragma unroll
            for (int m = 0; m < 2; ++m)
#pragma unroll
                for (int n = 0; n < 2; ++n) {
                    const int c_mn = nmn[m][n];
                    if (c_mn > 0 && pim[m] > 0 && pjn[n] > 0) {
                        lsum += (double)c_mn * invB *
                                (lg[c_mn] + lgB - lg[pim[m]] - lg[pjn[n]]);
                        ++lcnt;
                    }
                }
        }
    }

    __shared__ double ssum[256];
    __shared__ int scnt[256];
    __shared__ int lastFlag;
    ssum[threadIdx.x] = lsum;
    scnt[threadIdx.x] = lcnt;
    __syncthreads();
    for (int off = 128; off > 0; off >>= 1) {
        if (threadIdx.x < off) {
            ssum[threadIdx.x] += ssum[threadIdx.x + off];
            scnt[threadIdx.x] += scnt[threadIdx.x + off];
        }
        __syncthreads();
    }
    if (threadIdx.x == 0) {
        bsum[i] = ssum[0];
        bcnt[i] = scnt[0];
        __threadfence();
        lastFlag = (atomicAdd(done, 1) == MIGRID - 1);
    }
    __syncthreads();
    if (!lastFlag) return;

    __threadfence();
    double s2 = bsum[threadIdx.x] + bsum[threadIdx.x + 256];
    int c2 = bcnt[threadIdx.x] + bcnt[threadIdx.x + 256];
    __syncthreads();
    ssum[threadIdx.x] = s2;
    scnt[threadIdx.x] = c2;
    __syncthreads();
    for (int off = 128; off > 0; off >>= 1) {
        if (threadIdx.x < off) {
            ssum[threadIdx.x] += ssum[threadIdx.x + off];
            scnt[threadIdx.x] += scnt[threadIdx.x + off];
        }
        __syncthreads();
    }
    if (threadIdx.x == 0) out[0] = (float)(ssum[0] / (double)scnt[0]);
}

// ---------------------------------------------------------------------------
extern "C" void kernel_launch(void* const* d_in, const int* in_sizes, int n_in,
                              void* d_out, int out_size, void* d_ws, size_t ws_size,
                              hipStream_t stream) {
    const float* bits = (const float*)d_in[0];
    char* ws = (char*)d_ws;
    u64*            packed = (u64*)ws;                                   // 2 MB
    unsigned short* Cp     = (unsigned short*)(ws + (2u << 20));         // 16 MB
    double*         lg     = (double*)(ws + (18u << 20));                // 256 KB + 8 B
    int*            c1     = (int*)(ws + (18u << 20) + (512u << 10));    // 2 KB
    int*            done   = (int*)(ws + (18u << 20) + (516u << 10));    // 4 B
    double*         bsum   = (double*)(ws + (18u << 20) + (576u << 10)); // 4 KB
    int*            bcnt   = (int*)(ws + (18u << 20) + (640u << 10));    // 2 KB

    pack_kernel<<<512, 256, 0, stream>>>(bits, packed, lg, c1, done);
    gram_kernel<<<NTILE * NSLICE, 256, 0, stream>>>(packed, Cp, c1);
    mi_kernel<<<MIGRID, 256, 0, stream>>>(Cp, c1, lg, bsum, bcnt, done, (float*)d_out);
}